// Round 3
// baseline (699.072 us; speedup 1.0000x reference)
//
#include <hip/hip_runtime.h>

// out[b,k,p] = bias[k] + sum_{c in group k} w[c] * in[b,c,p]
// B=8, C=64, K=12, P=512*512. Pure streaming, memory-bound:
// 537 MB read + 101 MB write = 638 MB  ->  ~100 us floor at 6.4 TB/s.
// v3: 4x float4 per thread -> 4 KiB contiguous per wave per channel stream
//     (DRAM page locality; v2's 1 KiB-per-stream hops suspected as the
//     60%-of-peak cause). 512 blocks, 8 waves/CU. NT loads/stores kept.

#define NB 8
#define NC 64
#define NK 12
#define NP (512 * 512)
#define NPV (NP / 4)          // float4 per (b,c) plane = 65536
#define F4 4                  // float4 per thread
#define BLOCK 256
#define TILE (BLOCK * F4)                 // 1024 float4 per block
#define BLOCKS_PER_B (NPV / TILE)         // 64

typedef float v4f __attribute__((ext_vector_type(4)));

__global__ __launch_bounds__(BLOCK) void
hier_invert_kernel(const float* __restrict__ in,
                   const float* __restrict__ w,
                   const float* __restrict__ bias,
                   float* __restrict__ out) {
    const int tid = threadIdx.x;
    const int b    = blockIdx.x >> 6;            // blockIdx / 64
    const int pblk = (blockIdx.x & 63) << 10;    // (blockIdx % 64) * 1024
    const int p = pblk + tid;                    // f4 slots p, p+256, p+512, p+768

    const v4f* __restrict__ in4 =
        (const v4f*)in + (long long)b * NC * NPV + p;
    v4f* __restrict__ out4 =
        (v4f*)out + (long long)b * NK * NPV + p;

    // group boundaries (prefix sums of group sizes), compile-time constants
    constexpr int gs[NK + 1] = {0, 1, 4, 14, 20, 28, 38, 46, 52, 57, 59, 62, 64};

#pragma unroll
    for (int k = 0; k < NK; ++k) {
        const float bk = bias[k];                // uniform -> s_load
        v4f acc0 = {bk, bk, bk, bk};
        v4f acc1 = acc0, acc2 = acc0, acc3 = acc0;
#pragma unroll
        for (int c = gs[k]; c < gs[k + 1]; ++c) {
            const v4f* src = &in4[(long long)c * NPV];
            const float wc = w[c];               // uniform -> s_load
            const v4f v0 = __builtin_nontemporal_load(src);
            const v4f v1 = __builtin_nontemporal_load(src + BLOCK);
            const v4f v2 = __builtin_nontemporal_load(src + 2 * BLOCK);
            const v4f v3 = __builtin_nontemporal_load(src + 3 * BLOCK);
            acc0 += wc * v0;
            acc1 += wc * v1;
            acc2 += wc * v2;
            acc3 += wc * v3;
        }
        v4f* dst = &out4[(long long)k * NPV];
        __builtin_nontemporal_store(acc0, dst);
        __builtin_nontemporal_store(acc1, dst + BLOCK);
        __builtin_nontemporal_store(acc2, dst + 2 * BLOCK);
        __builtin_nontemporal_store(acc3, dst + 3 * BLOCK);
    }
}

extern "C" void kernel_launch(void* const* d_in, const int* in_sizes, int n_in,
                              void* d_out, int out_size, void* d_ws, size_t ws_size,
                              hipStream_t stream) {
    const float* in   = (const float*)d_in[0];   // [8,64,512,512] fp32
    const float* w    = (const float*)d_in[1];   // [64] fp32
    const float* bias = (const float*)d_in[2];   // [12] fp32
    float* out        = (float*)d_out;           // [8,12,512,512] fp32

    const int grid = NB * BLOCKS_PER_B;          // 512
    hier_invert_kernel<<<grid, BLOCK, 0, stream>>>(in, w, bias, out);
}